// Round 2
// baseline (160.536 us; speedup 1.0000x reference)
//
#include <hip/hip_runtime.h>

#define Bz   8
#define Lseq 2048
#define Din  128
#define Eo   64
#define TS   72     // attn LDS tile row stride (elements)
#define XS   136    // proj LDS tile row stride (elements)

typedef float f32x4 __attribute__((ext_vector_type(4)));
typedef __bf16 bf16x8 __attribute__((ext_vector_type(8), may_alias));
typedef float f32x4a __attribute__((ext_vector_type(4), may_alias));
typedef unsigned int u32x4 __attribute__((ext_vector_type(4), may_alias));

// ---------------------------------------------------------------------------
// Split the three W matrices [Din][Eo] fp32 into transposed hi/lo bf16 pairs:
// wT_hi/lo[3][Eo][Din].  hi = bf16(w), lo = bf16(w - hi)  (~17-bit mantissa).
// ---------------------------------------------------------------------------
__global__ __launch_bounds__(256) void split_w_kernel(
    const float* __restrict__ Wq, const float* __restrict__ Wk,
    const float* __restrict__ Wv,
    __bf16* __restrict__ hi, __bf16* __restrict__ lo)
{
    const float* W = (blockIdx.x == 0) ? Wq : (blockIdx.x == 1) ? Wk : Wv;
    __bf16* h = hi + (size_t)blockIdx.x * Eo * Din;
    __bf16* l = lo + (size_t)blockIdx.x * Eo * Din;
    for (int i = threadIdx.x; i < Din * Eo; i += 256) {
        int d = i >> 6, e = i & (Eo - 1);
        float w = W[i];
        __bf16 wh = (__bf16)w;
        h[e * Din + d] = wh;
        l[e * Din + d] = (__bf16)(w - (float)wh);
    }
}

// ---------------------------------------------------------------------------
// Projection with split-precision inputs: q = (x_hi+x_lo) @ (W_hi+W_lo),
// keeping hi*hi + lo*hi + hi*lo (fp32 accumulate). One block = 64 rows.
// mode 0: store hi/lo bf16 pair row-major [row][Eo]   (for q, k)
// mode 1: store single bf16 TRANSPOSED per batch [b][Eo][Lseq]  (for v)
// W fragments read straight from global (L2-resident, pre-split/transposed).
// ---------------------------------------------------------------------------
__global__ __launch_bounds__(256) void proj_kernel(
    const float* __restrict__ x,        // [Bz*Lseq][Din] fp32
    const __bf16* __restrict__ wT_hi,   // [Eo][Din]
    const __bf16* __restrict__ wT_lo,   // [Eo][Din]
    __bf16* __restrict__ out_hi,        // mode 0
    __bf16* __restrict__ out_lo,        // mode 0
    __bf16* __restrict__ outT,          // mode 1: [Bz][Eo][Lseq]
    int mode)
{
    __shared__ alignas(16) __bf16 xh[64 * XS];
    __shared__ alignas(16) __bf16 xl[64 * XS];

    const int t = threadIdx.x;
    const int row0 = blockIdx.x * 64;

    // stage x tile: 64 rows x 128 d, fp32 -> hi/lo bf16
    #pragma unroll
    for (int it = 0; it < 4; ++it) {
        int idx = t + it * 256;          // 1024 groups of 8 elements
        int r = idx >> 4;
        int c = (idx & 15) << 3;
        const float* src = x + (size_t)(row0 + r) * Din + c;
        f32x4a a = *(const f32x4a*)src;
        f32x4a b = *(const f32x4a*)(src + 4);
        __bf16* dh = &xh[r * XS + c];
        __bf16* dl = &xl[r * XS + c];
        #pragma unroll
        for (int j = 0; j < 4; ++j) {
            __bf16 h = (__bf16)a[j];
            dh[j] = h; dl[j] = (__bf16)(a[j] - (float)h);
        }
        #pragma unroll
        for (int j = 0; j < 4; ++j) {
            __bf16 h = (__bf16)b[j];
            dh[4 + j] = h; dl[4 + j] = (__bf16)(b[j] - (float)h);
        }
    }
    __syncthreads();

    const int lane = t & 63, wv = t >> 6;
    const int m = lane & 15, quad = lane >> 4;

    bf16x8 ah[4], al[4];
    #pragma unroll
    for (int kc = 0; kc < 4; ++kc) {
        ah[kc] = *(const bf16x8*)&xh[(wv * 16 + m) * XS + kc * 32 + quad * 8];
        al[kc] = *(const bf16x8*)&xl[(wv * 16 + m) * XS + kc * 32 + quad * 8];
    }

    f32x4 acc[4] = {{0,0,0,0},{0,0,0,0},{0,0,0,0},{0,0,0,0}};
    #pragma unroll
    for (int kc = 0; kc < 4; ++kc) {
        #pragma unroll
        for (int nt = 0; nt < 4; ++nt) {
            const size_t wo = (size_t)(nt * 16 + m) * Din + kc * 32 + quad * 8;
            bf16x8 wh = *(const bf16x8*)(wT_hi + wo);
            bf16x8 wl = *(const bf16x8*)(wT_lo + wo);
            acc[nt] = __builtin_amdgcn_mfma_f32_16x16x32_bf16(ah[kc], wh, acc[nt], 0, 0, 0);
            acc[nt] = __builtin_amdgcn_mfma_f32_16x16x32_bf16(al[kc], wh, acc[nt], 0, 0, 0);
            acc[nt] = __builtin_amdgcn_mfma_f32_16x16x32_bf16(ah[kc], wl, acc[nt], 0, 0, 0);
        }
    }

    // C layout: col = nt*16+m, row = quad*4 + r
    if (mode == 0) {
        #pragma unroll
        for (int nt = 0; nt < 4; ++nt)
            #pragma unroll
            for (int r = 0; r < 4; ++r) {
                int gr = row0 + wv * 16 + quad * 4 + r;
                float v = acc[nt][r];
                __bf16 h = (__bf16)v;
                out_hi[(size_t)gr * Eo + nt * 16 + m] = h;
                out_lo[(size_t)gr * Eo + nt * 16 + m] = (__bf16)(v - (float)h);
            }
    } else {
        #pragma unroll
        for (int nt = 0; nt < 4; ++nt)
            #pragma unroll
            for (int r = 0; r < 4; ++r) {
                int gr = row0 + wv * 16 + quad * 4 + r;
                int bb = gr >> 11;                 // /Lseq
                int l  = gr & (Lseq - 1);
                int e  = nt * 16 + m;
                outT[((size_t)(bb * Eo + e)) * Lseq + l] = (__bf16)acc[nt][r];
            }
    }
}

// ---------------------------------------------------------------------------
// Flash attention with split-precision logits:
//   S = q_hi k_hi + q_hi k_lo + q_lo k_hi   (fp32 acc, ~17-bit inputs)
// One block = (batch, 64 q rows); 4 waves x 16 q rows; 64-key tiles.
// ---------------------------------------------------------------------------
__global__ __launch_bounds__(256) void attn_kernel(
    const __bf16* __restrict__ qh_g, const __bf16* __restrict__ ql_g,
    const __bf16* __restrict__ kh_g, const __bf16* __restrict__ kl_g,
    const __bf16* __restrict__ vtb,   // [Bz][Eo][Lseq]
    float* __restrict__ out)          // [Bz*Lseq][Eo] fp32
{
    __shared__ alignas(16) __bf16 qth[64 * TS];
    __shared__ alignas(16) __bf16 qtl[64 * TS];
    __shared__ alignas(16) __bf16 kth[64 * TS];
    __shared__ alignas(16) __bf16 ktl[64 * TS];
    __shared__ alignas(16) __bf16 vtl[64 * TS];         // vt[e][key]
    __shared__ alignas(16) __bf16 pt [4 * 16 * TS];     // per-wave P [16 q][64 key]

    const int t = threadIdx.x;
    const int bb = blockIdx.y;
    const int q0 = blockIdx.x * 64;

    // stage Q tiles (64 x 64, hi+lo)
    #pragma unroll
    for (int it = 0; it < 2; ++it) {
        int idx = t + it * 256;
        int r = idx >> 3, c = (idx & 7) << 3;
        size_t g = ((size_t)(bb * Lseq) + q0 + r) * Eo + c;
        *(u32x4*)&qth[r * TS + c] = *(const u32x4*)&qh_g[g];
        *(u32x4*)&qtl[r * TS + c] = *(const u32x4*)&ql_g[g];
    }

    const int lane = t & 63, wv = t >> 6;
    const int m = lane & 15, quad = lane >> 4;

    __syncthreads();

    bf16x8 aqh[2], aql[2];
    #pragma unroll
    for (int kc = 0; kc < 2; ++kc) {
        aqh[kc] = *(const bf16x8*)&qth[(wv * 16 + m) * TS + kc * 32 + quad * 8];
        aql[kc] = *(const bf16x8*)&qtl[(wv * 16 + m) * TS + kc * 32 + quad * 8];
    }

    f32x4 Oacc[4] = {{0,0,0,0},{0,0,0,0},{0,0,0,0},{0,0,0,0}};
    float mrun[4], lrun[4];
    #pragma unroll
    for (int r = 0; r < 4; ++r) { mrun[r] = -INFINITY; lrun[r] = 0.f; }

    for (int kt = 0; kt < Lseq / 64; ++kt) {
        __syncthreads();   // previous tile fully consumed
        // stage K hi/lo tiles [key][d] and V^T tile [e][key]
        #pragma unroll
        for (int it = 0; it < 2; ++it) {
            int idx = t + it * 256;
            int r = idx >> 3, c = (idx & 7) << 3;
            size_t g = ((size_t)(bb * Lseq) + kt * 64 + r) * Eo + c;
            *(u32x4*)&kth[r * TS + c] = *(const u32x4*)&kh_g[g];
            *(u32x4*)&ktl[r * TS + c] = *(const u32x4*)&kl_g[g];
            *(u32x4*)&vtl[r * TS + c] =
                *(const u32x4*)&vtb[((size_t)(bb * Eo) + r) * Lseq + kt * 64 + c];
        }
        __syncthreads();

        // QK^T split-precision: S[16 q][64 keys] in 4 accumulators
        f32x4 s[4];
        #pragma unroll
        for (int n4 = 0; n4 < 4; ++n4) {
            f32x4 acc = {0, 0, 0, 0};
            #pragma unroll
            for (int kc = 0; kc < 2; ++kc) {
                bf16x8 bkh = *(const bf16x8*)&kth[(n4 * 16 + m) * TS + kc * 32 + quad * 8];
                bf16x8 bkl = *(const bf16x8*)&ktl[(n4 * 16 + m) * TS + kc * 32 + quad * 8];
                acc = __builtin_amdgcn_mfma_f32_16x16x32_bf16(aqh[kc], bkh, acc, 0, 0, 0);
                acc = __builtin_amdgcn_mfma_f32_16x16x32_bf16(aqh[kc], bkl, acc, 0, 0, 0);
                acc = __builtin_amdgcn_mfma_f32_16x16x32_bf16(aql[kc], bkh, acc, 0, 0, 0);
            }
            s[n4] = acc;
        }

        // online softmax per row (row = quad*4 + r)
        float alpha[4];
        #pragma unroll
        for (int r = 0; r < 4; ++r) {
            float tm = fmaxf(fmaxf(s[0][r], s[1][r]), fmaxf(s[2][r], s[3][r]));
            tm = fmaxf(tm, __shfl_xor(tm, 1));
            tm = fmaxf(tm, __shfl_xor(tm, 2));
            tm = fmaxf(tm, __shfl_xor(tm, 4));
            tm = fmaxf(tm, __shfl_xor(tm, 8));
            float mn = fmaxf(mrun[r], tm);
            float al = __expf(mrun[r] - mn);
            float rs = 0.f;
            #pragma unroll
            for (int n4 = 0; n4 < 4; ++n4) {
                float p = __expf(s[n4][r] - mn);
                s[n4][r] = p;
                rs += p;
            }
            rs += __shfl_xor(rs, 1);
            rs += __shfl_xor(rs, 2);
            rs += __shfl_xor(rs, 4);
            rs += __shfl_xor(rs, 8);
            lrun[r] = lrun[r] * al + rs;
            mrun[r] = mn;
            alpha[r] = al;
        }
        #pragma unroll
        for (int nt = 0; nt < 4; ++nt)
            #pragma unroll
            for (int r = 0; r < 4; ++r)
                Oacc[nt][r] *= alpha[r];

        // P (C-layout) -> LDS -> A-layout fragments
        #pragma unroll
        for (int n4 = 0; n4 < 4; ++n4)
            #pragma unroll
            for (int r = 0; r < 4; ++r)
                pt[wv * 16 * TS + (quad * 4 + r) * TS + n4 * 16 + m] = (__bf16)s[n4][r];

        #pragma unroll
        for (int kc = 0; kc < 2; ++kc) {
            bf16x8 ap = *(const bf16x8*)&pt[wv * 16 * TS + m * TS + kc * 32 + quad * 8];
            #pragma unroll
            for (int nt = 0; nt < 4; ++nt) {
                bf16x8 bv = *(const bf16x8*)&vtl[(nt * 16 + m) * TS + kc * 32 + quad * 8];
                Oacc[nt] = __builtin_amdgcn_mfma_f32_16x16x32_bf16(ap, bv, Oacc[nt], 0, 0, 0);
            }
        }
    }

    // epilogue: O / l
    float inv[4];
    #pragma unroll
    for (int r = 0; r < 4; ++r) inv[r] = 1.f / lrun[r];
    #pragma unroll
    for (int nt = 0; nt < 4; ++nt)
        #pragma unroll
        for (int r = 0; r < 4; ++r) {
            int gq = q0 + wv * 16 + quad * 4 + r;
            out[((size_t)(bb * Lseq) + gq) * Eo + nt * 16 + m] = Oacc[nt][r] * inv[r];
        }
}

extern "C" void kernel_launch(void* const* d_in, const int* in_sizes, int n_in,
                              void* d_out, int out_size, void* d_ws, size_t ws_size,
                              hipStream_t stream) {
    const float* query = (const float*)d_in[0];
    const float* key   = (const float*)d_in[1];
    const float* Wq    = (const float*)d_in[2];
    const float* Wk    = (const float*)d_in[3];
    const float* Wv    = (const float*)d_in[4];
    float* out = (float*)d_out;

    const size_t NQ = (size_t)Bz * Lseq * Eo;      // 1 Mi elements
    __bf16* qh  = (__bf16*)d_ws;                   // each 2 MB
    __bf16* ql  = qh + NQ;
    __bf16* kh  = ql + NQ;
    __bf16* kl  = kh + NQ;
    __bf16* vtb = kl + NQ;                         // [Bz][Eo][Lseq]
    __bf16* wTh = vtb + NQ;                        // [3][Eo][Din]
    __bf16* wTl = wTh + (size_t)3 * Eo * Din;

    split_w_kernel<<<dim3(3), 256, 0, stream>>>(Wq, Wk, Wv, wTh, wTl);

    const int nblk = Bz * Lseq / 64;               // 256
    proj_kernel<<<dim3(nblk), 256, 0, stream>>>(
        query, wTh + 0 * Eo * Din, wTl + 0 * Eo * Din, qh, ql, vtb, 0);
    proj_kernel<<<dim3(nblk), 256, 0, stream>>>(
        key,   wTh + 1 * Eo * Din, wTl + 1 * Eo * Din, kh, kl, vtb, 0);
    proj_kernel<<<dim3(nblk), 256, 0, stream>>>(
        key,   wTh + 2 * Eo * Din, wTl + 2 * Eo * Din, kh, kl, vtb, 1);

    attn_kernel<<<dim3(Lseq / 64, Bz), 256, 0, stream>>>(qh, ql, kh, kl, vtb, out);
}

// Round 3
// 154.926 us; speedup vs baseline: 1.0362x; 1.0362x over previous
//
#include <hip/hip_runtime.h>

#define Bz     8
#define Lseq   2048
#define Din    128
#define Eo     64
#define TS     72     // attn LDS tile row stride (elements)
#define XS     136    // proj LDS tile row stride (elements)
#define KSPLIT 4      // key-range split for attn occupancy

typedef float f32x4 __attribute__((ext_vector_type(4)));
typedef __bf16 bf16x8 __attribute__((ext_vector_type(8), may_alias));
typedef float f32x4a __attribute__((ext_vector_type(4), may_alias));
typedef unsigned int u32x4 __attribute__((ext_vector_type(4), may_alias));

// ---------------------------------------------------------------------------
// Split the three W matrices [Din][Eo] fp32 into transposed hi/lo bf16 pairs:
// wT_hi/lo[3][Eo][Din].  hi = bf16(w), lo = bf16(w - hi)  (~17-bit mantissa).
// grid (3, 8): x = matrix, y = slice of the 8192 elements.
// ---------------------------------------------------------------------------
__global__ __launch_bounds__(256) void split_w_kernel(
    const float* __restrict__ Wq, const float* __restrict__ Wk,
    const float* __restrict__ Wv,
    __bf16* __restrict__ hi, __bf16* __restrict__ lo)
{
    const float* W = (blockIdx.x == 0) ? Wq : (blockIdx.x == 1) ? Wk : Wv;
    __bf16* h = hi + (size_t)blockIdx.x * Eo * Din;
    __bf16* l = lo + (size_t)blockIdx.x * Eo * Din;
    int base = blockIdx.y * (Din * Eo / 8);
    for (int i = base + threadIdx.x; i < base + Din * Eo / 8; i += 256) {
        int d = i >> 6, e = i & (Eo - 1);
        float w = W[i];
        __bf16 wh = (__bf16)w;
        h[e * Din + d] = wh;
        l[e * Din + d] = (__bf16)(w - (float)wh);
    }
}

// ---------------------------------------------------------------------------
// Fused projections, one launch, grid 512:
//   blocks [0,256):   q = query @ Wq  -> hi/lo pair, row-major
//   blocks [256,512): k = key @ Wk    -> hi/lo pair, row-major
//                     v = key @ Wv    -> single bf16, TRANSPOSED [b][Eo][Lseq]
// Split-precision MFMA: hi*hi + lo*hi + hi*lo, fp32 accumulate.
// ---------------------------------------------------------------------------
__global__ __launch_bounds__(256) void proj_kernel(
    const float* __restrict__ query, const float* __restrict__ key,
    const __bf16* __restrict__ wTh,   // [3][Eo][Din]
    const __bf16* __restrict__ wTl,
    __bf16* __restrict__ qh, __bf16* __restrict__ ql,
    __bf16* __restrict__ kh, __bf16* __restrict__ kl,
    __bf16* __restrict__ vtb)         // [Bz][Eo][Lseq]
{
    __shared__ alignas(16) __bf16 xh[64 * XS];
    __shared__ alignas(16) __bf16 xl[64 * XS];

    const int t = threadIdx.x;
    const bool is_q = blockIdx.x < 256;
    const int row0 = (is_q ? blockIdx.x : blockIdx.x - 256) * 64;
    const float* x = is_q ? query : key;

    // stage x tile: 64 rows x 128 d, fp32 -> hi/lo bf16
    #pragma unroll
    for (int it = 0; it < 4; ++it) {
        int idx = t + it * 256;          // 1024 groups of 8 elements
        int r = idx >> 4;
        int c = (idx & 15) << 3;
        const float* src = x + (size_t)(row0 + r) * Din + c;
        f32x4a a = *(const f32x4a*)src;
        f32x4a b = *(const f32x4a*)(src + 4);
        __bf16* dh = &xh[r * XS + c];
        __bf16* dl = &xl[r * XS + c];
        #pragma unroll
        for (int j = 0; j < 4; ++j) {
            __bf16 h = (__bf16)a[j];
            dh[j] = h; dl[j] = (__bf16)(a[j] - (float)h);
        }
        #pragma unroll
        for (int j = 0; j < 4; ++j) {
            __bf16 h = (__bf16)b[j];
            dh[4 + j] = h; dl[4 + j] = (__bf16)(b[j] - (float)h);
        }
    }
    __syncthreads();

    const int lane = t & 63, wv = t >> 6;
    const int m = lane & 15, quad = lane >> 4;

    bf16x8 ah[4], al[4];
    #pragma unroll
    for (int kc = 0; kc < 4; ++kc) {
        ah[kc] = *(const bf16x8*)&xh[(wv * 16 + m) * XS + kc * 32 + quad * 8];
        al[kc] = *(const bf16x8*)&xl[(wv * 16 + m) * XS + kc * 32 + quad * 8];
    }

    const __bf16* w0h = wTh + (size_t)(is_q ? 0 : 1) * Eo * Din;
    const __bf16* w0l = wTl + (size_t)(is_q ? 0 : 1) * Eo * Din;

    f32x4 acc[4] = {{0,0,0,0},{0,0,0,0},{0,0,0,0},{0,0,0,0}};
    #pragma unroll
    for (int kc = 0; kc < 4; ++kc) {
        #pragma unroll
        for (int nt = 0; nt < 4; ++nt) {
            const size_t wo = (size_t)(nt * 16 + m) * Din + kc * 32 + quad * 8;
            bf16x8 wh = *(const bf16x8*)(w0h + wo);
            bf16x8 wl = *(const bf16x8*)(w0l + wo);
            acc[nt] = __builtin_amdgcn_mfma_f32_16x16x32_bf16(ah[kc], wh, acc[nt], 0, 0, 0);
            acc[nt] = __builtin_amdgcn_mfma_f32_16x16x32_bf16(al[kc], wh, acc[nt], 0, 0, 0);
            acc[nt] = __builtin_amdgcn_mfma_f32_16x16x32_bf16(ah[kc], wl, acc[nt], 0, 0, 0);
        }
    }

    __bf16* oh = is_q ? qh : kh;
    __bf16* ol = is_q ? ql : kl;
    // C layout: col = nt*16+m, row = quad*4 + r
    #pragma unroll
    for (int nt = 0; nt < 4; ++nt)
        #pragma unroll
        for (int r = 0; r < 4; ++r) {
            int gr = row0 + wv * 16 + quad * 4 + r;
            float v = acc[nt][r];
            __bf16 h = (__bf16)v;
            oh[(size_t)gr * Eo + nt * 16 + m] = h;
            ol[(size_t)gr * Eo + nt * 16 + m] = (__bf16)(v - (float)h);
        }

    if (!is_q) {
        const __bf16* w1h = wTh + (size_t)2 * Eo * Din;
        const __bf16* w1l = wTl + (size_t)2 * Eo * Din;
        f32x4 acc1[4] = {{0,0,0,0},{0,0,0,0},{0,0,0,0},{0,0,0,0}};
        #pragma unroll
        for (int kc = 0; kc < 4; ++kc) {
            #pragma unroll
            for (int nt = 0; nt < 4; ++nt) {
                const size_t wo = (size_t)(nt * 16 + m) * Din + kc * 32 + quad * 8;
                bf16x8 wh = *(const bf16x8*)(w1h + wo);
                bf16x8 wl = *(const bf16x8*)(w1l + wo);
                acc1[nt] = __builtin_amdgcn_mfma_f32_16x16x32_bf16(ah[kc], wh, acc1[nt], 0, 0, 0);
                acc1[nt] = __builtin_amdgcn_mfma_f32_16x16x32_bf16(al[kc], wh, acc1[nt], 0, 0, 0);
                acc1[nt] = __builtin_amdgcn_mfma_f32_16x16x32_bf16(ah[kc], wl, acc1[nt], 0, 0, 0);
            }
        }
        #pragma unroll
        for (int nt = 0; nt < 4; ++nt)
            #pragma unroll
            for (int r = 0; r < 4; ++r) {
                int gr = row0 + wv * 16 + quad * 4 + r;
                int bb = gr >> 11;                 // /Lseq
                int l  = gr & (Lseq - 1);
                int e  = nt * 16 + m;
                vtb[((size_t)(bb * Eo + e)) * Lseq + l] = (__bf16)acc1[nt][r];
            }
    }
}

// ---------------------------------------------------------------------------
// Flash attention, key-split: block = (qtile, batch, ksplit); 4 waves x 16 q.
// Each block covers Lseq/KSPLIT keys, writes UNNORMALIZED O-partial + (m,l).
// S = q_hi k_hi + q_hi k_lo + q_lo k_hi (fp32 acc). LDS: q-staging buffer is
// reused as the per-wave P transpose buffer (46 KB total -> 3 blocks/CU).
// ---------------------------------------------------------------------------
__global__ __launch_bounds__(256) void attn_kernel(
    const __bf16* __restrict__ qh_g, const __bf16* __restrict__ ql_g,
    const __bf16* __restrict__ kh_g, const __bf16* __restrict__ kl_g,
    const __bf16* __restrict__ vtb,   // [Bz][Eo][Lseq]
    float* __restrict__ Opart,        // [KSPLIT][Bz*Lseq][Eo] unnormalized
    float* __restrict__ ms,           // [KSPLIT][Bz*Lseq]
    float* __restrict__ ls)           // [KSPLIT][Bz*Lseq]
{
    __shared__ alignas(16) __bf16 kth[64 * TS];
    __shared__ alignas(16) __bf16 ktl[64 * TS];
    __shared__ alignas(16) __bf16 vtl[64 * TS];       // vt[e][key]
    __shared__ alignas(16) __bf16 qbuf[2 * 64 * TS];  // q staging; reused as P

    const int t = threadIdx.x;
    const int bb = blockIdx.y;
    const int q0 = blockIdx.x * 64;
    const int kz = blockIdx.z;

    // stage Q tiles (64 x 64, hi+lo)
    #pragma unroll
    for (int it = 0; it < 2; ++it) {
        int idx = t + it * 256;
        int r = idx >> 3, c = (idx & 7) << 3;
        size_t g = ((size_t)(bb * Lseq) + q0 + r) * Eo + c;
        *(u32x4*)&qbuf[r * TS + c]           = *(const u32x4*)&qh_g[g];
        *(u32x4*)&qbuf[64 * TS + r * TS + c] = *(const u32x4*)&ql_g[g];
    }

    const int lane = t & 63, wv = t >> 6;
    const int m = lane & 15, quad = lane >> 4;

    __syncthreads();

    bf16x8 aqh[2], aql[2];
    #pragma unroll
    for (int kc = 0; kc < 2; ++kc) {
        aqh[kc] = *(const bf16x8*)&qbuf[(wv * 16 + m) * TS + kc * 32 + quad * 8];
        aql[kc] = *(const bf16x8*)&qbuf[64 * TS + (wv * 16 + m) * TS + kc * 32 + quad * 8];
    }
    __bf16* pt = qbuf;   // reuse (needs 4*16*TS <= 64*TS)

    f32x4 Oacc[4] = {{0,0,0,0},{0,0,0,0},{0,0,0,0},{0,0,0,0}};
    float mrun[4], lrun[4];
    #pragma unroll
    for (int r = 0; r < 4; ++r) { mrun[r] = -INFINITY; lrun[r] = 0.f; }

    const int TILES = Lseq / 64 / KSPLIT;
    for (int kt0 = 0; kt0 < TILES; ++kt0) {
        const int kt = kz * TILES + kt0;
        __syncthreads();   // previous tile (and q frags / prev P) fully consumed
        #pragma unroll
        for (int it = 0; it < 2; ++it) {
            int idx = t + it * 256;
            int r = idx >> 3, c = (idx & 7) << 3;
            size_t g = ((size_t)(bb * Lseq) + kt * 64 + r) * Eo + c;
            *(u32x4*)&kth[r * TS + c] = *(const u32x4*)&kh_g[g];
            *(u32x4*)&ktl[r * TS + c] = *(const u32x4*)&kl_g[g];
            *(u32x4*)&vtl[r * TS + c] =
                *(const u32x4*)&vtb[((size_t)(bb * Eo) + r) * Lseq + kt * 64 + c];
        }
        __syncthreads();

        // QK^T split-precision: S[16 q][64 keys] in 4 accumulators
        f32x4 s[4];
        #pragma unroll
        for (int n4 = 0; n4 < 4; ++n4) {
            f32x4 acc = {0, 0, 0, 0};
            #pragma unroll
            for (int kc = 0; kc < 2; ++kc) {
                bf16x8 bkh = *(const bf16x8*)&kth[(n4 * 16 + m) * TS + kc * 32 + quad * 8];
                bf16x8 bkl = *(const bf16x8*)&ktl[(n4 * 16 + m) * TS + kc * 32 + quad * 8];
                acc = __builtin_amdgcn_mfma_f32_16x16x32_bf16(aqh[kc], bkh, acc, 0, 0, 0);
                acc = __builtin_amdgcn_mfma_f32_16x16x32_bf16(aqh[kc], bkl, acc, 0, 0, 0);
                acc = __builtin_amdgcn_mfma_f32_16x16x32_bf16(aql[kc], bkh, acc, 0, 0, 0);
            }
            s[n4] = acc;
        }

        // online softmax per row (row = quad*4 + r), reduce over 16 lanes
        float alpha[4];
        #pragma unroll
        for (int r = 0; r < 4; ++r) {
            float tm = fmaxf(fmaxf(s[0][r], s[1][r]), fmaxf(s[2][r], s[3][r]));
            tm = fmaxf(tm, __shfl_xor(tm, 1));
            tm = fmaxf(tm, __shfl_xor(tm, 2));
            tm = fmaxf(tm, __shfl_xor(tm, 4));
            tm = fmaxf(tm, __shfl_xor(tm, 8));
            float mn = fmaxf(mrun[r], tm);
            float al = __expf(mrun[r] - mn);
            float rs = 0.f;
            #pragma unroll
            for (int n4 = 0; n4 < 4; ++n4) {
                float p = __expf(s[n4][r] - mn);
                s[n4][r] = p;
                rs += p;
            }
            rs += __shfl_xor(rs, 1);
            rs += __shfl_xor(rs, 2);
            rs += __shfl_xor(rs, 4);
            rs += __shfl_xor(rs, 8);
            lrun[r] = lrun[r] * al + rs;
            mrun[r] = mn;
            alpha[r] = al;
        }
        #pragma unroll
        for (int nt = 0; nt < 4; ++nt)
            #pragma unroll
            for (int r = 0; r < 4; ++r)
                Oacc[nt][r] *= alpha[r];

        // P (C-layout) -> LDS -> A-layout fragments (per-wave region, no barrier)
        #pragma unroll
        for (int n4 = 0; n4 < 4; ++n4)
            #pragma unroll
            for (int r = 0; r < 4; ++r)
                pt[wv * 16 * TS + (quad * 4 + r) * TS + n4 * 16 + m] = (__bf16)s[n4][r];

        #pragma unroll
        for (int kc = 0; kc < 2; ++kc) {
            bf16x8 ap = *(const bf16x8*)&pt[wv * 16 * TS + m * TS + kc * 32 + quad * 8];
            #pragma unroll
            for (int nt = 0; nt < 4; ++nt) {
                bf16x8 bv = *(const bf16x8*)&vtl[(nt * 16 + m) * TS + kc * 32 + quad * 8];
                Oacc[nt] = __builtin_amdgcn_mfma_f32_16x16x32_bf16(ap, bv, Oacc[nt], 0, 0, 0);
            }
        }
    }

    // epilogue: write unnormalized partial + (m,l)
    const size_t rbase = (size_t)kz * Bz * Lseq + (size_t)bb * Lseq;
    #pragma unroll
    for (int nt = 0; nt < 4; ++nt)
        #pragma unroll
        for (int r = 0; r < 4; ++r) {
            int gq = q0 + wv * 16 + quad * 4 + r;
            Opart[(rbase + gq) * Eo + nt * 16 + m] = Oacc[nt][r];
        }
    if (m == 0) {
        #pragma unroll
        for (int r = 0; r < 4; ++r) {
            int gq = q0 + wv * 16 + quad * 4 + r;
            ms[rbase + gq] = mrun[r];
            ls[rbase + gq] = lrun[r];
        }
    }
}

// ---------------------------------------------------------------------------
// Combine KSPLIT partials: out = sum_s e^{m_s - M} O_s / sum_s e^{m_s - M} l_s
// ---------------------------------------------------------------------------
__global__ __launch_bounds__(256) void combine_kernel(
    const float* __restrict__ Opart, const float* __restrict__ ms,
    const float* __restrict__ ls, float* __restrict__ out)
{
    const size_t R = (size_t)Bz * Lseq;
    size_t idx = (size_t)blockIdx.x * 256 + threadIdx.x;  // over R*Eo
    size_t row = idx >> 6;
    float mv[KSPLIT];
    float M = -INFINITY;
    #pragma unroll
    for (int s = 0; s < KSPLIT; ++s) {
        mv[s] = ms[s * R + row];
        M = fmaxf(M, mv[s]);
    }
    float acc = 0.f, lsum = 0.f;
    #pragma unroll
    for (int s = 0; s < KSPLIT; ++s) {
        float w = __expf(mv[s] - M);
        acc  += w * Opart[s * R * Eo + idx];
        lsum += w * ls[s * R + row];
    }
    out[idx] = acc / lsum;
}

extern "C" void kernel_launch(void* const* d_in, const int* in_sizes, int n_in,
                              void* d_out, int out_size, void* d_ws, size_t ws_size,
                              hipStream_t stream) {
    const float* query = (const float*)d_in[0];
    const float* key   = (const float*)d_in[1];
    const float* Wq    = (const float*)d_in[2];
    const float* Wk    = (const float*)d_in[3];
    const float* Wv    = (const float*)d_in[4];
    float* out = (float*)d_out;

    const size_t NQ = (size_t)Bz * Lseq * Eo;      // 1 Mi elements
    __bf16* qh  = (__bf16*)d_ws;                   // 5 x 2 MB bf16
    __bf16* ql  = qh + NQ;
    __bf16* kh  = ql + NQ;
    __bf16* kl  = kh + NQ;
    __bf16* vtb = kl + NQ;
    __bf16* wTh = vtb + NQ;                        // [3][Eo][Din]
    __bf16* wTl = wTh + (size_t)3 * Eo * Din;
    float*  Opart = (float*)(wTl + (size_t)3 * Eo * Din);  // KSPLIT x 4 MB
    float*  ms    = Opart + (size_t)KSPLIT * NQ;
    float*  ls    = ms + (size_t)KSPLIT * Bz * Lseq;

    split_w_kernel<<<dim3(3, 8), 256, 0, stream>>>(Wq, Wk, Wv, wTh, wTl);
    proj_kernel<<<dim3(512), 256, 0, stream>>>(query, key, wTh, wTl,
                                               qh, ql, kh, kl, vtb);
    attn_kernel<<<dim3(Lseq / 64, Bz, KSPLIT), 256, 0, stream>>>(
        qh, ql, kh, kl, vtb, Opart, ms, ls);
    combine_kernel<<<dim3((int)(NQ / 256)), 256, 0, stream>>>(Opart, ms, ls, out);
}